// Round 8
// baseline (443.920 us; speedup 1.0000x reference)
//
#include <hip/hip_runtime.h>
#include <hip/hip_fp16.h>

#define N_NODES 50000
#define N_EDGES 800000

typedef _Float16 half8 __attribute__((ext_vector_type(8)));
typedef _Float16 f16x4 __attribute__((ext_vector_type(4)));
typedef float floatx4 __attribute__((ext_vector_type(4)));

// ---------------------------------------------------------------------------
// setup (strided): row_ptr lower_bound over sorted src; degree histogram
// (bins[128], zeroed by hipMemsetAsync before this kernel); lw0 cast;
// lw1/lw2 fold (64x256 fp32) -> planar K=192 fp16 [o, ch*64+f],
// ch {0:h0+h1, 1:a2, 2:a3}.
// ---------------------------------------------------------------------------
__global__ __launch_bounds__(256) void setup_kernel(const int* __restrict__ src,
                                                    int* __restrict__ row_ptr,
                                                    int* __restrict__ bins,
                                                    const float* __restrict__ lw0,
                                                    const float* __restrict__ lw1,
                                                    const float* __restrict__ lw2,
                                                    _Float16* __restrict__ w0p,
                                                    _Float16* __restrict__ w1p,
                                                    _Float16* __restrict__ w2p) {
    const int gid = blockIdx.x * 256 + threadIdx.x;
    const int gstride = gridDim.x * 256;
    for (int idx = gid; idx <= N_NODES; idx += gstride) {
        int lo = 0, hi = N_EDGES;
        while (lo < hi) {
            int mid = (lo + hi) >> 1;
            if (src[mid] < idx) lo = mid + 1; else hi = mid;
        }
        row_ptr[idx] = lo;
    }
    // degree histogram (independent binary searches; no dependence on the
    // row_ptr[] values written by other threads this launch)
    for (int i = gid; i < N_NODES; i += gstride) {
        int lo = 0, hi = N_EDGES;
        while (lo < hi) { int m = (lo + hi) >> 1; if (src[m] < i) lo = m + 1; else hi = m; }
        int lo1 = lo, hi1 = N_EDGES;
        while (lo1 < hi1) { int m = (lo1 + hi1) >> 1; if (src[m] < i + 1) lo1 = m + 1; else hi1 = m; }
        int deg = lo1 - lo;
        atomicAdd(&bins[deg < 127 ? deg : 127], 1);
    }
    for (int idx = gid; idx < 64 * 128; idx += gstride) w0p[idx] = (_Float16)lw0[idx];
    for (int idx = gid; idx < 64 * 192; idx += gstride) {
        int o = idx / 192, r = idx % 192;
        int ch = r >> 6, f = r & 63;
        float v1, v2;
        if (ch == 0) {
            v1 = lw1[o * 256 + f * 4 + 0] + lw1[o * 256 + f * 4 + 1];
            v2 = lw2[o * 256 + f * 4 + 0] + lw2[o * 256 + f * 4 + 1];
        } else if (ch == 1) {
            v1 = lw1[o * 256 + f * 4 + 2];
            v2 = lw2[o * 256 + f * 4 + 2];
        } else {
            v1 = lw1[o * 256 + f * 4 + 3];
            v2 = lw2[o * 256 + f * 4 + 3];
        }
        w1p[idx] = (_Float16)v1;
        w2p[idx] = (_Float16)v2;
    }
}

// ---------------------------------------------------------------------------
// scan: bins counts -> DESCENDING-degree exclusive offsets (longest-job-first
// scheduling: highest-degree nodes land at order[0..]). Single block, 128 thr.
// ---------------------------------------------------------------------------
__global__ __launch_bounds__(128) void scan_kernel(int* __restrict__ bins) {
    __shared__ int tmp[128];
    const int t = threadIdx.x;
    const int cnt = bins[127 - t];          // reversed: t=0 <-> deg 127
    tmp[t] = cnt;
    __syncthreads();
    for (int o = 1; o < 128; o <<= 1) {
        int u = (t >= o) ? tmp[t - o] : 0;
        __syncthreads();
        tmp[t] += u;
        __syncthreads();
    }
    bins[127 - t] = tmp[t] - cnt;           // exclusive offset in desc order
}

// ---------------------------------------------------------------------------
// scatter: order[] = node ids grouped by degree (descending). Position within
// a bin is arbitrary (atomicAdd) — per-node aggregation is order-independent.
// ---------------------------------------------------------------------------
__global__ __launch_bounds__(256) void scatter_kernel(const int* __restrict__ row_ptr,
                                                      int* __restrict__ bins,
                                                      int* __restrict__ order) {
    const int gid = blockIdx.x * 256 + threadIdx.x;
    const int gstride = gridDim.x * 256;
    for (int i = gid; i < N_NODES; i += gstride) {
        int deg = row_ptr[i + 1] - row_ptr[i];
        int pos = atomicAdd(&bins[deg < 127 ? deg : 127], 1);
        order[pos] = i;
    }
}

// ---------------------------------------------------------------------------
// lin via MFMA 16x16x32 f16 (layout verified R8). 4 waves, 16 rows x 64 cols
// per wave. TIn=float folds the x cast in. Stores E = exp(score).
// ---------------------------------------------------------------------------
template <typename TIn, int K>
__global__ __launch_bounds__(256) void lin_kernel(const TIn* __restrict__ in,
                                                  const _Float16* __restrict__ w,
                                                  const float* __restrict__ b,
                                                  const float* __restrict__ aw,
                                                  _Float16* __restrict__ h,
                                                  float2* __restrict__ s, int n) {
    const int t = threadIdx.x;
    const int l = t & 63;
    const int wv = t >> 6;
    const int arow = l & 15;
    const int kg = l >> 4;
    const long rowbase = (long)blockIdx.x * 64 + wv * 16;
    long arow_g = rowbase + arow;
    if (arow_g >= n) arow_g = n - 1;

    floatx4 acc[4] = {};

    for (int kc = 0; kc < K; kc += 32) {
        const int ks = kc + kg * 8;
        half8 a;
        if (sizeof(TIn) == 4) {
            const TIn* ap = in + arow_g * K + ks;
            #pragma unroll
            for (int j = 0; j < 8; ++j) a[j] = (_Float16)ap[j];
        } else {
            a = *(const half8*)((const _Float16*)in + arow_g * K + ks);
        }
        #pragma unroll
        for (int ct = 0; ct < 4; ++ct) {
            half8 bb = *(const half8*)(w + (long)(ct * 16 + arow) * K + ks);
            acc[ct] = __builtin_amdgcn_mfma_f32_16x16x32_f16(a, bb, acc[ct], 0, 0, 0);
        }
    }

    const int c = l & 15;
    const int rq = l >> 4;
    float bias[4], a2c[4], a3c[4];
    #pragma unroll
    for (int ct = 0; ct < 4; ++ct) {
        int col = ct * 16 + c;
        bias[ct] = b[col];
        a2c[ct] = aw[2 * 128 + col] + aw[2 * 128 + 64 + col];
        a3c[ct] = aw[3 * 128 + col] + aw[3 * 128 + 64 + col];
    }
    #pragma unroll
    for (int r = 0; r < 4; ++r) {
        long row = rowbase + rq * 4 + r;
        bool ok = row < n;
        float q2 = 0.f, q3 = 0.f;
        _Float16 hv[4];
        #pragma unroll
        for (int ct = 0; ct < 4; ++ct) {
            float u = acc[ct][r] + bias[ct];
            u = u > 0.f ? u : 0.2f * u;
            q2 += u * a2c[ct];
            q3 += u * a3c[ct];
            hv[ct] = (_Float16)u;
        }
        if (ok) {
            #pragma unroll
            for (int ct = 0; ct < 4; ++ct) h[row * 64 + ct * 16 + c] = hv[ct];
        }
        #pragma unroll
        for (int o = 1; o < 16; o <<= 1) {
            q2 += __shfl_xor(q2, o);
            q3 += __shfl_xor(q3, o);
        }
        if (c == 0 && ok) s[row] = make_float2(__expf(q2), __expf(q3));
    }
}

// ---------------------------------------------------------------------------
// R19 layer kernel: EXACT R2 fused structure (quarter-per-node agg + LDS g +
// MFMA next-lin; 64-VGPR codegen proven), with ONE change: blocks process
// nodes through order[] (degree-grouped, descending). Within a wave all 4
// nodes have (near-)identical degree -> md == deg for everyone -> the
// wave-max padding term (x1.55 edge-slots at random grouping) collapses to
// batch-of-4 rounding (~x1.07). R18's dst-bucketing reverted (it regressed).
// ---------------------------------------------------------------------------
template <int FINAL>
__global__ __launch_bounds__(256) void layer_kernel(const _Float16* __restrict__ hfeat,
                                                    const float2* __restrict__ E,
                                                    const int* __restrict__ dst,
                                                    const int* __restrict__ row_ptr,
                                                    const int* __restrict__ order,
                                                    const _Float16* __restrict__ w,
                                                    const float* __restrict__ b,
                                                    const float* __restrict__ aw,
                                                    _Float16* __restrict__ h_out,
                                                    float2* __restrict__ s_out,
                                                    float* __restrict__ out_f) {
    __shared__ _Float16 g_lds[16][200];
    __shared__ float2 spart[4][16];
    __shared__ int ordt[16];

    const int t = threadIdx.x;
    const int l = t & 63;
    const int wv = t >> 6;
    const int q = l >> 4;      // phase A: node slot | phase B: k-group
    const int fl = l & 15;     // phase A: feature quad | phase B: row/col lane
    const int base = blockIdx.x * 16;

    if (t < 16) ordt[t] = order[base + t];
    __syncthreads();

    const int i = ordt[wv * 4 + q];            // this quarter's node

    const int r0 = row_ptr[i];
    const int deg = row_ptr[i + 1] - r0;
    int md = deg;
    md = max(md, __shfl_xor(md, 16));
    md = max(md, __shfl_xor(md, 32));          // wave-uniform max degree (~deg)

    float am[4] = {}, a2[4] = {}, a3[4] = {};
    float S2 = 0.f, S3 = 0.f;
    const int safew = deg > 0 ? r0 + deg - 1 : 0;   // clamp for padded lanes

    for (int c0 = 0; c0 < md; c0 += 16) {
        const int dl = dst[min(r0 + c0 + fl, safew)];  // 16 edge ids / quarter
        const int jn = min(16, md - c0);               // uniform inner bound
        for (int j = 0; j < jn; j += 4) {
            int dg[4]; float vm[4];
            #pragma unroll
            for (int g = 0; g < 4; ++g) {
                const int sl = j + g;                  // <= 15 always
                dg[g] = __shfl(dl, (q << 4) | sl);     // broadcast in-quarter
                vm[g] = (c0 + sl < deg) ? 1.f : 0.f;
            }
            f16x4 hv[4]; float2 Ev[4];
            #pragma unroll
            for (int g = 0; g < 4; ++g) {
                hv[g] = *(const f16x4*)(hfeat + (long)dg[g] * 64 + fl * 4);
                Ev[g] = E[dg[g]];                      // quarter-uniform bcast
            }
            #pragma unroll
            for (int g = 0; g < 4; ++g) {
                const float e2 = vm[g] * Ev[g].x, e3 = vm[g] * Ev[g].y;
                S2 += e2; S3 += e3;
                #pragma unroll
                for (int k = 0; k < 4; ++k) {
                    const float hf = (float)hv[g][k];
                    am[k] += vm[g] * hf;
                    a2[k] += e2 * hf;
                    a3[k] += e3 * hf;
                }
            }
        }
    }

    const float inv_deg = deg > 0 ? 1.f / (float)deg : 0.f;
    const float i2 = deg > 0 ? 1.f / S2 : 0.f;
    const float i3 = deg > 0 ? 1.f / S3 : 0.f;

    if (FINAL) {
        floatx4 o;
        #pragma unroll
        for (int k = 0; k < 4; ++k)
            o[k] = fmaxf(0.5f * inv_deg * am[k] + 0.25f * (a2[k] * i2 + a3[k] * i3), 0.f);
        *(floatx4*)(out_f + (long)i * 64 + fl * 4) = o;
        return;
    }

    // g row into LDS (all 16 lanes of the quarter write their own quads)
    {
        const int nl = wv * 4 + q;
        f16x4 o0, o1, o2;
        #pragma unroll
        for (int k = 0; k < 4; ++k) {
            o0[k] = (_Float16)fmaxf(am[k] * inv_deg, 0.f);
            o1[k] = (_Float16)fmaxf(a2[k] * i2, 0.f);
            o2[k] = (_Float16)fmaxf(a3[k] * i3, 0.f);
        }
        *(f16x4*)(&g_lds[nl][fl * 4])       = o0;
        *(f16x4*)(&g_lds[nl][64 + fl * 4])  = o1;
        *(f16x4*)(&g_lds[nl][128 + fl * 4]) = o2;
    }
    __syncthreads();

    // Phase B (proven): lin for these 16 rows. Wave wv = cols wv*16..+15.
    floatx4 acc = {};
    #pragma unroll
    for (int kc = 0; kc < 192; kc += 32) {
        const int ks = kc + q * 8;
        half8 a = *(const half8*)(&g_lds[fl][ks]);
        half8 bb = *(const half8*)(w + (long)(wv * 16 + fl) * 192 + ks);
        acc = __builtin_amdgcn_mfma_f32_16x16x32_f16(a, bb, acc, 0, 0, 0);
    }

    const int col = wv * 16 + fl;
    const float bias = b[col];
    const float a2c = aw[2 * 128 + col] + aw[2 * 128 + 64 + col];
    const float a3c = aw[3 * 128 + col] + aw[3 * 128 + 64 + col];
    #pragma unroll
    for (int r = 0; r < 4; ++r) {
        const int row = q * 4 + r;
        float u = acc[r] + bias;
        u = u > 0.f ? u : 0.2f * u;
        h_out[(long)ordt[row] * 64 + col] = (_Float16)u;
        float q2 = u * a2c, q3 = u * a3c;
        #pragma unroll
        for (int o = 1; o < 16; o <<= 1) {
            q2 += __shfl_xor(q2, o);
            q3 += __shfl_xor(q3, o);
        }
        if (fl == 0) spart[wv][row] = make_float2(q2, q3);
    }
    __syncthreads();
    if (t < 16) {
        const float2 p0 = spart[0][t], p1 = spart[1][t], p2 = spart[2][t], p3 = spart[3][t];
        s_out[ordt[t]] = make_float2(__expf(p0.x + p1.x + p2.x + p3.x),
                                     __expf(p0.y + p1.y + p2.y + p3.y));
    }
}

// ---------------------------------------------------------------------------
extern "C" void kernel_launch(void* const* d_in, const int* in_sizes, int n_in,
                              void* d_out, int out_size, void* d_ws, size_t ws_size,
                              hipStream_t stream) {
    const float* x = (const float*)d_in[0];
    const float* lw0 = (const float*)d_in[1];
    const float* lb0 = (const float*)d_in[2];
    const float* aw0 = (const float*)d_in[3];
    const float* lw1 = (const float*)d_in[5];
    const float* lb1 = (const float*)d_in[6];
    const float* aw1 = (const float*)d_in[7];
    const float* lw2 = (const float*)d_in[9];
    const float* lb2 = (const float*)d_in[10];
    const float* aw2 = (const float*)d_in[11];
    const int* src = (const int*)d_in[13];
    const int* dst = (const int*)d_in[14];
    float* out = (float*)d_out;

    const int N = N_NODES;

    // ws layout: hA,hB: N*64 f16 | sA,sB: N float2 | w0p 64*128 f16
    //            | w1p,w2p 64*192 f16 | row_ptr N+1 | bins 128 | order N
    _Float16* hA = (_Float16*)d_ws;
    _Float16* hB = hA + (size_t)N * 64;
    float2* sA = (float2*)(hB + (size_t)N * 64);
    float2* sB = sA + N;
    _Float16* w0p = (_Float16*)(sB + N);
    _Float16* w1p = w0p + 64 * 128;
    _Float16* w2p = w1p + 64 * 192;
    int* row_ptr = (int*)(w2p + 64 * 192);
    int* bins = row_ptr + N + 1;
    int* order = bins + 128;

    const int lin_grid = (N + 63) / 64;      // 782
    const int layer_grid = N / 16;           // 3125

    hipMemsetAsync(bins, 0, 128 * sizeof(int), stream);
    setup_kernel<<<196, 256, 0, stream>>>(src, row_ptr, bins, lw0, lw1, lw2,
                                          w0p, w1p, w2p);
    scan_kernel<<<1, 128, 0, stream>>>(bins);
    scatter_kernel<<<196, 256, 0, stream>>>(row_ptr, bins, order);
    lin_kernel<float, 128><<<lin_grid, 256, 0, stream>>>(x, w0p, lb0, aw0, hA, sA, N);
    layer_kernel<0><<<layer_grid, 256, 0, stream>>>(hA, sA, dst, row_ptr, order,
                                                    w1p, lb1, aw1, hB, sB, out);
    layer_kernel<0><<<layer_grid, 256, 0, stream>>>(hB, sB, dst, row_ptr, order,
                                                    w2p, lb2, aw2, hA, sA, out);
    layer_kernel<1><<<layer_grid, 256, 0, stream>>>(hA, sA, dst, row_ptr, order,
                                                    w2p, lb2, aw2, hB, sB, out);
}

// Round 9
// 209.293 us; speedup vs baseline: 2.1210x; 2.1210x over previous
//
#include <hip/hip_runtime.h>
#include <hip/hip_fp16.h>

#define N_NODES 50000
#define N_EDGES 800000

typedef _Float16 half8 __attribute__((ext_vector_type(8)));
typedef _Float16 f16x4 __attribute__((ext_vector_type(4)));
typedef float floatx4 __attribute__((ext_vector_type(4)));

// ---------------------------------------------------------------------------
// setup (strided): row_ptr lower_bound over sorted src (NO atomics — R8's
// global-atomic histogram here was 131us of contention); lw0 cast; lw1/lw2
// fold (64x256 fp32) -> planar K=192 fp16 [o, ch*64+f], ch {0:h0+h1,1:a2,2:a3}.
// ---------------------------------------------------------------------------
__global__ __launch_bounds__(256) void setup_kernel(const int* __restrict__ src,
                                                    int* __restrict__ row_ptr,
                                                    const float* __restrict__ lw0,
                                                    const float* __restrict__ lw1,
                                                    const float* __restrict__ lw2,
                                                    _Float16* __restrict__ w0p,
                                                    _Float16* __restrict__ w1p,
                                                    _Float16* __restrict__ w2p) {
    const int gid = blockIdx.x * 256 + threadIdx.x;
    const int gstride = gridDim.x * 256;
    for (int idx = gid; idx <= N_NODES; idx += gstride) {
        int lo = 0, hi = N_EDGES;
        while (lo < hi) {
            int mid = (lo + hi) >> 1;
            if (src[mid] < idx) lo = mid + 1; else hi = mid;
        }
        row_ptr[idx] = lo;
    }
    for (int idx = gid; idx < 64 * 128; idx += gstride) w0p[idx] = (_Float16)lw0[idx];
    for (int idx = gid; idx < 64 * 192; idx += gstride) {
        int o = idx / 192, r = idx % 192;
        int ch = r >> 6, f = r & 63;
        float v1, v2;
        if (ch == 0) {
            v1 = lw1[o * 256 + f * 4 + 0] + lw1[o * 256 + f * 4 + 1];
            v2 = lw2[o * 256 + f * 4 + 0] + lw2[o * 256 + f * 4 + 1];
        } else if (ch == 1) {
            v1 = lw1[o * 256 + f * 4 + 2];
            v2 = lw2[o * 256 + f * 4 + 2];
        } else {
            v1 = lw1[o * 256 + f * 4 + 3];
            v2 = lw2[o * 256 + f * 4 + 3];
        }
        w1p[idx] = (_Float16)v1;
        w2p[idx] = (_Float16)v2;
    }
}

// ---------------------------------------------------------------------------
// hist: per-block LDS histogram of degrees (reads row_ptr from the prior
// dispatch), one global flush per bin per block. bins[] pre-zeroed.
// ---------------------------------------------------------------------------
__global__ __launch_bounds__(256) void hist_kernel(const int* __restrict__ row_ptr,
                                                   int* __restrict__ bins) {
    __shared__ int lh[128];
    const int t = threadIdx.x;
    if (t < 128) lh[t] = 0;
    __syncthreads();
    const int gid = blockIdx.x * 256 + t;
    const int gstride = gridDim.x * 256;
    for (int i = gid; i < N_NODES; i += gstride) {
        int deg = row_ptr[i + 1] - row_ptr[i];
        atomicAdd(&lh[deg < 127 ? deg : 127], 1);      // LDS atomic: cheap
    }
    __syncthreads();
    if (t < 128 && lh[t] > 0) atomicAdd(&bins[t], lh[t]);
}

// ---------------------------------------------------------------------------
// scan: bins counts -> DESCENDING-degree exclusive offsets (longest-first).
// ---------------------------------------------------------------------------
__global__ __launch_bounds__(128) void scan_kernel(int* __restrict__ bins) {
    __shared__ int tmp[128];
    const int t = threadIdx.x;
    const int cnt = bins[127 - t];          // reversed: t=0 <-> deg 127
    tmp[t] = cnt;
    __syncthreads();
    for (int o = 1; o < 128; o <<= 1) {
        int u = (t >= o) ? tmp[t - o] : 0;
        __syncthreads();
        tmp[t] += u;
        __syncthreads();
    }
    bins[127 - t] = tmp[t] - cnt;           // exclusive offset in desc order
}

// ---------------------------------------------------------------------------
// scatter: ONE node per thread (grid 196*256 >= N). Local rank via LDS
// atomicAdd return value; block reserves per-bin global chunks (<=128 global
// atomics/block); order[] = node ids grouped by degree (descending).
// ---------------------------------------------------------------------------
__global__ __launch_bounds__(256) void scatter_kernel(const int* __restrict__ row_ptr,
                                                      int* __restrict__ bins,
                                                      int* __restrict__ order) {
    __shared__ int lh[128];
    __shared__ int lbase[128];
    const int t = threadIdx.x;
    if (t < 128) lh[t] = 0;
    __syncthreads();
    const int i = blockIdx.x * 256 + t;
    int deg = 0, lrank = 0;
    const bool ok = i < N_NODES;
    if (ok) {
        deg = row_ptr[i + 1] - row_ptr[i];
        deg = deg < 127 ? deg : 127;
        lrank = atomicAdd(&lh[deg], 1);                // LDS atomic: cheap
    }
    __syncthreads();
    if (t < 128 && lh[t] > 0) lbase[t] = atomicAdd(&bins[t], lh[t]);
    __syncthreads();
    if (ok) order[lbase[deg] + lrank] = i;
}

// ---------------------------------------------------------------------------
// lin via MFMA 16x16x32 f16 (layout verified R8). 4 waves, 16 rows x 64 cols
// per wave. TIn=float folds the x cast in. Stores E = exp(score).
// ---------------------------------------------------------------------------
template <typename TIn, int K>
__global__ __launch_bounds__(256) void lin_kernel(const TIn* __restrict__ in,
                                                  const _Float16* __restrict__ w,
                                                  const float* __restrict__ b,
                                                  const float* __restrict__ aw,
                                                  _Float16* __restrict__ h,
                                                  float2* __restrict__ s, int n) {
    const int t = threadIdx.x;
    const int l = t & 63;
    const int wv = t >> 6;
    const int arow = l & 15;
    const int kg = l >> 4;
    const long rowbase = (long)blockIdx.x * 64 + wv * 16;
    long arow_g = rowbase + arow;
    if (arow_g >= n) arow_g = n - 1;

    floatx4 acc[4] = {};

    for (int kc = 0; kc < K; kc += 32) {
        const int ks = kc + kg * 8;
        half8 a;
        if (sizeof(TIn) == 4) {
            const TIn* ap = in + arow_g * K + ks;
            #pragma unroll
            for (int j = 0; j < 8; ++j) a[j] = (_Float16)ap[j];
        } else {
            a = *(const half8*)((const _Float16*)in + arow_g * K + ks);
        }
        #pragma unroll
        for (int ct = 0; ct < 4; ++ct) {
            half8 bb = *(const half8*)(w + (long)(ct * 16 + arow) * K + ks);
            acc[ct] = __builtin_amdgcn_mfma_f32_16x16x32_f16(a, bb, acc[ct], 0, 0, 0);
        }
    }

    const int c = l & 15;
    const int rq = l >> 4;
    float bias[4], a2c[4], a3c[4];
    #pragma unroll
    for (int ct = 0; ct < 4; ++ct) {
        int col = ct * 16 + c;
        bias[ct] = b[col];
        a2c[ct] = aw[2 * 128 + col] + aw[2 * 128 + 64 + col];
        a3c[ct] = aw[3 * 128 + col] + aw[3 * 128 + 64 + col];
    }
    #pragma unroll
    for (int r = 0; r < 4; ++r) {
        long row = rowbase + rq * 4 + r;
        bool ok = row < n;
        float q2 = 0.f, q3 = 0.f;
        _Float16 hv[4];
        #pragma unroll
        for (int ct = 0; ct < 4; ++ct) {
            float u = acc[ct][r] + bias[ct];
            u = u > 0.f ? u : 0.2f * u;
            q2 += u * a2c[ct];
            q3 += u * a3c[ct];
            hv[ct] = (_Float16)u;
        }
        if (ok) {
            #pragma unroll
            for (int ct = 0; ct < 4; ++ct) h[row * 64 + ct * 16 + c] = hv[ct];
        }
        #pragma unroll
        for (int o = 1; o < 16; o <<= 1) {
            q2 += __shfl_xor(q2, o);
            q3 += __shfl_xor(q3, o);
        }
        if (c == 0 && ok) s[row] = make_float2(__expf(q2), __expf(q3));
    }
}

// ---------------------------------------------------------------------------
// layer kernel: EXACT R2 fused structure (quarter-per-node agg + LDS g +
// MFMA next-lin; 64-VGPR codegen proven), blocks take nodes through order[]
// (degree-grouped desc) -> within a wave all 4 nodes have ~equal degree ->
// wave-max padding (x1.55 at random grouping) collapses to ~x1.07.
// (R8 verified correctness of the order[] indirection; this round only
// fixes the preprocessing cost.)
// ---------------------------------------------------------------------------
template <int FINAL>
__global__ __launch_bounds__(256) void layer_kernel(const _Float16* __restrict__ hfeat,
                                                    const float2* __restrict__ E,
                                                    const int* __restrict__ dst,
                                                    const int* __restrict__ row_ptr,
                                                    const int* __restrict__ order,
                                                    const _Float16* __restrict__ w,
                                                    const float* __restrict__ b,
                                                    const float* __restrict__ aw,
                                                    _Float16* __restrict__ h_out,
                                                    float2* __restrict__ s_out,
                                                    float* __restrict__ out_f) {
    __shared__ _Float16 g_lds[16][200];
    __shared__ float2 spart[4][16];
    __shared__ int ordt[16];

    const int t = threadIdx.x;
    const int l = t & 63;
    const int wv = t >> 6;
    const int q = l >> 4;      // phase A: node slot | phase B: k-group
    const int fl = l & 15;     // phase A: feature quad | phase B: row/col lane
    const int base = blockIdx.x * 16;

    if (t < 16) ordt[t] = order[base + t];
    __syncthreads();

    const int i = ordt[wv * 4 + q];            // this quarter's node

    const int r0 = row_ptr[i];
    const int deg = row_ptr[i + 1] - r0;
    int md = deg;
    md = max(md, __shfl_xor(md, 16));
    md = max(md, __shfl_xor(md, 32));          // wave-uniform max degree (~deg)

    float am[4] = {}, a2[4] = {}, a3[4] = {};
    float S2 = 0.f, S3 = 0.f;
    const int safew = deg > 0 ? r0 + deg - 1 : 0;   // clamp for padded lanes

    for (int c0 = 0; c0 < md; c0 += 16) {
        const int dl = dst[min(r0 + c0 + fl, safew)];  // 16 edge ids / quarter
        const int jn = min(16, md - c0);               // uniform inner bound
        for (int j = 0; j < jn; j += 4) {
            int dg[4]; float vm[4];
            #pragma unroll
            for (int g = 0; g < 4; ++g) {
                const int sl = j + g;                  // <= 15 always
                dg[g] = __shfl(dl, (q << 4) | sl);     // broadcast in-quarter
                vm[g] = (c0 + sl < deg) ? 1.f : 0.f;
            }
            f16x4 hv[4]; float2 Ev[4];
            #pragma unroll
            for (int g = 0; g < 4; ++g) {
                hv[g] = *(const f16x4*)(hfeat + (long)dg[g] * 64 + fl * 4);
                Ev[g] = E[dg[g]];                      // quarter-uniform bcast
            }
            #pragma unroll
            for (int g = 0; g < 4; ++g) {
                const float e2 = vm[g] * Ev[g].x, e3 = vm[g] * Ev[g].y;
                S2 += e2; S3 += e3;
                #pragma unroll
                for (int k = 0; k < 4; ++k) {
                    const float hf = (float)hv[g][k];
                    am[k] += vm[g] * hf;
                    a2[k] += e2 * hf;
                    a3[k] += e3 * hf;
                }
            }
        }
    }

    const float inv_deg = deg > 0 ? 1.f / (float)deg : 0.f;
    const float i2 = deg > 0 ? 1.f / S2 : 0.f;
    const float i3 = deg > 0 ? 1.f / S3 : 0.f;

    if (FINAL) {
        floatx4 o;
        #pragma unroll
        for (int k = 0; k < 4; ++k)
            o[k] = fmaxf(0.5f * inv_deg * am[k] + 0.25f * (a2[k] * i2 + a3[k] * i3), 0.f);
        *(floatx4*)(out_f + (long)i * 64 + fl * 4) = o;
        return;
    }

    // g row into LDS (all 16 lanes of the quarter write their own quads)
    {
        const int nl = wv * 4 + q;
        f16x4 o0, o1, o2;
        #pragma unroll
        for (int k = 0; k < 4; ++k) {
            o0[k] = (_Float16)fmaxf(am[k] * inv_deg, 0.f);
            o1[k] = (_Float16)fmaxf(a2[k] * i2, 0.f);
            o2[k] = (_Float16)fmaxf(a3[k] * i3, 0.f);
        }
        *(f16x4*)(&g_lds[nl][fl * 4])       = o0;
        *(f16x4*)(&g_lds[nl][64 + fl * 4])  = o1;
        *(f16x4*)(&g_lds[nl][128 + fl * 4]) = o2;
    }
    __syncthreads();

    // Phase B (proven): lin for these 16 rows. Wave wv = cols wv*16..+15.
    floatx4 acc = {};
    #pragma unroll
    for (int kc = 0; kc < 192; kc += 32) {
        const int ks = kc + q * 8;
        half8 a = *(const half8*)(&g_lds[fl][ks]);
        half8 bb = *(const half8*)(w + (long)(wv * 16 + fl) * 192 + ks);
        acc = __builtin_amdgcn_mfma_f32_16x16x32_f16(a, bb, acc, 0, 0, 0);
    }

    const int col = wv * 16 + fl;
    const float bias = b[col];
    const float a2c = aw[2 * 128 + col] + aw[2 * 128 + 64 + col];
    const float a3c = aw[3 * 128 + col] + aw[3 * 128 + 64 + col];
    #pragma unroll
    for (int r = 0; r < 4; ++r) {
        const int row = q * 4 + r;
        float u = acc[r] + bias;
        u = u > 0.f ? u : 0.2f * u;
        h_out[(long)ordt[row] * 64 + col] = (_Float16)u;
        float q2 = u * a2c, q3 = u * a3c;
        #pragma unroll
        for (int o = 1; o < 16; o <<= 1) {
            q2 += __shfl_xor(q2, o);
            q3 += __shfl_xor(q3, o);
        }
        if (fl == 0) spart[wv][row] = make_float2(q2, q3);
    }
    __syncthreads();
    if (t < 16) {
        const float2 p0 = spart[0][t], p1 = spart[1][t], p2 = spart[2][t], p3 = spart[3][t];
        s_out[ordt[t]] = make_float2(__expf(p0.x + p1.x + p2.x + p3.x),
                                     __expf(p0.y + p1.y + p2.y + p3.y));
    }
}

// ---------------------------------------------------------------------------
extern "C" void kernel_launch(void* const* d_in, const int* in_sizes, int n_in,
                              void* d_out, int out_size, void* d_ws, size_t ws_size,
                              hipStream_t stream) {
    const float* x = (const float*)d_in[0];
    const float* lw0 = (const float*)d_in[1];
    const float* lb0 = (const float*)d_in[2];
    const float* aw0 = (const float*)d_in[3];
    const float* lw1 = (const float*)d_in[5];
    const float* lb1 = (const float*)d_in[6];
    const float* aw1 = (const float*)d_in[7];
    const float* lw2 = (const float*)d_in[9];
    const float* lb2 = (const float*)d_in[10];
    const float* aw2 = (const float*)d_in[11];
    const int* src = (const int*)d_in[13];
    const int* dst = (const int*)d_in[14];
    float* out = (float*)d_out;

    const int N = N_NODES;

    // ws layout: hA,hB: N*64 f16 | sA,sB: N float2 | w0p 64*128 f16
    //            | w1p,w2p 64*192 f16 | row_ptr N+1 | bins 128 | order N
    _Float16* hA = (_Float16*)d_ws;
    _Float16* hB = hA + (size_t)N * 64;
    float2* sA = (float2*)(hB + (size_t)N * 64);
    float2* sB = sA + N;
    _Float16* w0p = (_Float16*)(sB + N);
    _Float16* w1p = w0p + 64 * 128;
    _Float16* w2p = w1p + 64 * 192;
    int* row_ptr = (int*)(w2p + 64 * 192);
    int* bins = row_ptr + N + 1;
    int* order = bins + 128;

    const int lin_grid = (N + 63) / 64;      // 782
    const int layer_grid = N / 16;           // 3125

    hipMemsetAsync(bins, 0, 128 * sizeof(int), stream);
    setup_kernel<<<196, 256, 0, stream>>>(src, row_ptr, lw0, lw1, lw2,
                                          w0p, w1p, w2p);
    hist_kernel<<<196, 256, 0, stream>>>(row_ptr, bins);
    scan_kernel<<<1, 128, 0, stream>>>(bins);
    scatter_kernel<<<196, 256, 0, stream>>>(row_ptr, bins, order);
    lin_kernel<float, 128><<<lin_grid, 256, 0, stream>>>(x, w0p, lb0, aw0, hA, sA, N);
    layer_kernel<0><<<layer_grid, 256, 0, stream>>>(hA, sA, dst, row_ptr, order,
                                                    w1p, lb1, aw1, hB, sB, out);
    layer_kernel<0><<<layer_grid, 256, 0, stream>>>(hB, sB, dst, row_ptr, order,
                                                    w2p, lb2, aw2, hA, sA, out);
    layer_kernel<1><<<layer_grid, 256, 0, stream>>>(hA, sA, dst, row_ptr, order,
                                                    w2p, lb2, aw2, hB, sB, out);
}